// Round 6
// baseline (198.851 us; speedup 1.0000x reference)
//
#include <hip/hip_runtime.h>
#include <math.h>

#define Bsz 8
#define Cch 512
#define Npx 1024
#define TOPK 12
#define BN (Bsz * Npx)

typedef __attribute__((ext_vector_type(8))) short bf16x8;
typedef __attribute__((ext_vector_type(4))) float f32x4;

__device__ __forceinline__ unsigned short f2bf(float x) {
    unsigned u = __float_as_uint(x);
    u += 0x7FFF + ((u >> 16) & 1);
    return (unsigned short)(u >> 16);
}
__device__ __forceinline__ float bf2f(unsigned short h) {
    return __uint_as_float(((unsigned)h) << 16);
}

// ---------------- reduction helpers ----------------
__device__ __forceinline__ float warp_sum64(float v) {
    for (int o = 32; o > 0; o >>= 1) v += __shfl_down(v, o);
    return v;
}
__device__ __forceinline__ float block_sum512(float v, float* s8) {
    v = warp_sum64(v);
    int lane = threadIdx.x & 63, w = threadIdx.x >> 6;
    __syncthreads();
    if (lane == 0) s8[w] = v;
    __syncthreads();
    float r = 0.f;
    #pragma unroll
    for (int k = 0; k < 8; k++) r += s8[k];
    return r;
}

// ---------------- 1: masked average pool (float4, single-barrier) -------------
// grid (Cch, Bsz), block 256
__global__ void k_pool(const float* __restrict__ sf, const int* __restrict__ mask,
                       float* __restrict__ FPo, float* __restrict__ BPo) {
    __shared__ float s4a[4], s4b[4], s4c[4];
    int c = blockIdx.x, b = blockIdx.y, t = threadIdx.x;
    const float4* f4 = (const float4*)(sf + ((size_t)b * Cch + c) * Npx);
    const int4* m4 = (const int4*)(mask + (size_t)b * Npx);
    float4 v = f4[t];
    int4 m = m4[t];
    float sumf = (m.x == 1 ? v.x : 0.f) + (m.y == 1 ? v.y : 0.f)
               + (m.z == 1 ? v.z : 0.f) + (m.w == 1 ? v.w : 0.f);
    float tot = v.x + v.y + v.z + v.w;
    float cf = (float)((m.x == 1) + (m.y == 1) + (m.z == 1) + (m.w == 1));
    sumf = warp_sum64(sumf);
    tot  = warp_sum64(tot);
    cf   = warp_sum64(cf);
    int lane = t & 63, w = t >> 6;
    if (lane == 0) { s4a[w] = sumf; s4b[w] = tot; s4c[w] = cf; }
    __syncthreads();
    if (t == 0) {
        float sA = s4a[0] + s4a[1] + s4a[2] + s4a[3];
        float sB = s4b[0] + s4b[1] + s4b[2] + s4b[3];
        float sC = s4c[0] + s4c[1] + s4c[2] + s4c[3];
        FPo[b * Cch + c] = sA / (sC + 1e-5f);
        BPo[b * Cch + c] = (sB - sA) / ((1024.f - sC) + 1e-5f);
    }
}

// ---------------- 2: pred logit + bf16 cast (block 512: 16 thr/pixel) ---------
// grid (Npx/32, Bsz), block 512. Also zeroes the 4 accumulator arrays
// (pdb, pnb, pdf, pqq) consumed by PV atomics, and the PV completion counters.
__global__ void __launch_bounds__(512) k_predcast(const float* __restrict__ fq,
                       const float* __restrict__ FP, const float* __restrict__ BP,
                       float* __restrict__ dsim, float* __restrict__ invn,
                       unsigned short* __restrict__ Ft, float* __restrict__ accs,
                       int* __restrict__ wcnt) {
    __shared__ float sFP[Cch], sBP[Cch], s8[8];
    __shared__ float rdf[16][32], rdb[16][32], rqq[16][32];
    __shared__ unsigned short S[32][522];   // odd dword stride -> conflict-free
    int b = blockIdx.y, t = threadIdx.x;
    int tx = t & 31, ty = t >> 5;           // ty in [0,16)
    int p0 = blockIdx.x * 32;
    int p = p0 + tx;
    if (t < 128) accs[(size_t)(t >> 5) * BN + b * Npx + p0 + (t & 31)] = 0.f;
    if (blockIdx.x == 0 && t == 0) wcnt[b] = 0;
    sFP[t] = FP[b * Cch + t];
    sBP[t] = BP[b * Cch + t];
    __syncthreads();
    float nf = sqrtf(block_sum512(sFP[t] * sFP[t], s8));
    float nb = sqrtf(block_sum512(sBP[t] * sBP[t], s8));
    const float* q = fq + (size_t)b * Cch * Npx + p;
    float df = 0.f, db = 0.f, qq = 0.f;
    int c0 = ty * 32;
    #pragma unroll 4
    for (int c = 0; c < 32; c += 2) {
        float v0 = q[(size_t)(c0 + c) * Npx];
        float v1 = q[(size_t)(c0 + c + 1) * Npx];
        df += v0 * sFP[c0 + c] + v1 * sFP[c0 + c + 1];
        db += v0 * sBP[c0 + c] + v1 * sBP[c0 + c + 1];
        qq += v0 * v0 + v1 * v1;
        unsigned pk = (unsigned)f2bf(v0) | ((unsigned)f2bf(v1) << 16);
        *(unsigned*)&S[tx][c0 + c] = pk;
    }
    rdf[ty][tx] = df; rdb[ty][tx] = db; rqq[ty][tx] = qq;
    __syncthreads();
    for (int s = 8; s > 0; s >>= 1) {
        if (ty < s) {
            rdf[ty][tx] += rdf[ty + s][tx];
            rdb[ty][tx] += rdb[ty + s][tx];
            rqq[ty][tx] += rqq[ty + s][tx];
        }
        __syncthreads();
    }
    if (ty == 0) {
        float nq = sqrtf(rqq[0][tx]);
        float simf = 10.f * rdf[0][tx] / fmaxf(nq * nf, 1e-8f);
        float simb = 10.f * rdb[0][tx] / fmaxf(nq * nb, 1e-8f);
        dsim[b * Npx + p] = simf - simb;
        invn[b * Npx + p] = 1.f / nq;
    }
    // write Ft rows (coalesced dword stores, conflict-free LDS dword reads)
    int w = t >> 6, lane = t & 63;           // 8 waves
    unsigned short* FtB = Ft + (size_t)b * Npx * Cch;
    for (int pr = w; pr < 32; pr += 8) {
        unsigned* dst = (unsigned*)(FtB + (size_t)(p0 + pr) * Cch);
        #pragma unroll
        for (int it = 0; it < 4; it++) {
            int d = it * 64 + lane;
            dst[d] = *(const unsigned*)&S[pr][d * 2];
        }
    }
}

// ---------------- 3: select + compact + prototypes + FP1/nf -------------------
// grid (2, Bsz), block 1024 (16 waves). x=0: fg, x=1: bg
__global__ void __launch_bounds__(1024) k_selcompact(const float* __restrict__ dsim,
                        const float* __restrict__ invn,
                        const unsigned short* __restrict__ Ft,
                        const float* __restrict__ FP,
                        int* __restrict__ nsf, int* __restrict__ nsb,
                        int* __restrict__ jf, int* __restrict__ jb,
                        float* __restrict__ ivg,
                        float* __restrict__ fgp, float* __restrict__ bgp,
                        float* __restrict__ FP1, float* __restrict__ nfv) {
    __shared__ int wsum[16];
    __shared__ int sns;
    __shared__ float sProto[16][512];       // 32 KB
    __shared__ float s16f[16];
    int b = blockIdx.y, t = threadIdx.x;
    int lane = t & 63, w = t >> 6;
    bool isf = (blockIdx.x == 0);
    float d = dsim[b * Npx + t];
    float key = isf ? d : -d;
    float thres = isf ? 0.8472979f : 0.4054651f;   // ln(0.7/0.3), ln(0.6/0.4)
    int flag = (key > thres) ? 1 : 0;
    int x = flag;
    #pragma unroll
    for (int o = 1; o < 64; o <<= 1) {
        int y = __shfl_up(x, o);
        if (lane >= o) x += y;
    }
    if (lane == 63) wsum[w] = x;
    __syncthreads();
    int base = 0, total = 0;
    #pragma unroll
    for (int k = 0; k < 16; k++) {
        int s = wsum[k];
        if (k < w) base += s;
        total += s;
    }
    int* jdst = (isf ? jf : jb) + b * Npx;
    if (total == 0) {
        // cold path: top-12 fallback (lower index wins ties)
        __shared__ int   sc[Npx];
        __shared__ float v[Npx];
        __shared__ float rv[Npx];
        __shared__ int   ri[Npx];
        v[t] = key; flag = 0;
        __syncthreads();
        for (int k = 0; k < TOPK; k++) {
            rv[t] = v[t]; ri[t] = t;
            __syncthreads();
            for (int s = 512; s > 0; s >>= 1) {
                if (t < s) {
                    float a = rv[t], bb = rv[t + s];
                    int ia = ri[t], ib = ri[t + s];
                    if (bb > a || (bb == a && ib < ia)) { rv[t] = bb; ri[t] = ib; }
                }
                __syncthreads();
            }
            int win = ri[0];
            if (t == win) { flag = 1; v[t] = -INFINITY; }
            __syncthreads();
        }
        sc[t] = flag;
        __syncthreads();
        for (int off = 1; off < 1024; off <<= 1) {
            int xx = (t >= off) ? sc[t - off] : 0;
            __syncthreads();
            sc[t] += xx;
            __syncthreads();
        }
        if (flag) {
            int pos = sc[t] - 1;
            jdst[pos] = t;
            if (!isf) ivg[b * Npx + pos] = invn[b * Npx + t];
        }
        if (t == 1023) sns = sc[1023];
    } else {
        if (flag) {
            int pos = base + x - 1;
            jdst[pos] = t;
            if (!isf) ivg[b * Npx + pos] = invn[b * Npx + t];
        }
        if (t == 0) sns = total;
    }
    __syncthreads();                         // jdst writes + sns visible to block
    int ns = sns;
    if (t == 0) (isf ? nsf : nsb)[b] = ns;
    // ---- prototype: mean of selected Ft rows (coalesced 1KB row reads) ----
    const unsigned short* FtB = Ft + (size_t)b * Npx * Cch;
    float facc[8] = {0.f, 0.f, 0.f, 0.f, 0.f, 0.f, 0.f, 0.f};
    int k = w;
    int row = (k < ns) ? jdst[k] : 0;
    while (k < ns) {
        int kn = k + 16;
        int rown = (kn < ns) ? jdst[kn] : 0;   // prefetch index
        bf16x8 vv = *(const bf16x8*)&FtB[(size_t)row * Cch + lane * 8];
        #pragma unroll
        for (int e = 0; e < 8; e++) facc[e] += bf2f((unsigned short)vv[e]);
        k = kn; row = rown;
    }
    #pragma unroll
    for (int e = 0; e < 8; e++) sProto[w][lane * 8 + e] = facc[e];
    __syncthreads();
    float fp1 = 0.f;
    if (t < 512) {
        float s = 0.f;
        #pragma unroll
        for (int q = 0; q < 16; q++) s += sProto[q][t];
        float pv = s / (float)ns;
        (isf ? fgp : bgp)[b * Cch + t] = pv;
        if (isf) {
            fp1 = 0.5f * FP[b * Cch + t] + 0.5f * pv;
            FP1[b * Cch + t] = fp1;
        }
    }
    if (isf) {
        // ||FP1|| for the final fg similarity
        float v2 = warp_sum64(fp1 * fp1);
        if (lane == 0) s16f[w] = v2;
        __syncthreads();
        if (t == 0) {
            float nn = 0.f;
            #pragma unroll
            for (int q = 0; q < 16; q++) nn += s16f[q];
            nfv[b] = sqrtf(nn);
        }
    }
}

// ---------------- 4: Gram(64x64)+exp  ||  gather-transpose Fg -----------------
// grid (16, 32, Bsz), block 256 (4 waves). K=64 staging.
//   y in [0,16):  gram tile i0=x*64, j0=y*64 -> G=exp(sim) bf16 (0 for j>=ns)
//   y in [16,32): transpose tile c0=(y-16)*32, j0=x*64 -> Fg[c][j]
// (denominator now computed inside PV -- no atomics/reduction here)
__global__ void __launch_bounds__(256) k_gram_fused(const unsigned short* __restrict__ Ft,
                        const int* __restrict__ jb, const int* __restrict__ nsb,
                        const float* __restrict__ invn, const float* __restrict__ ivg,
                        unsigned short* __restrict__ G, unsigned short* __restrict__ Fg) {
    int b = blockIdx.z;
    int ns = nsb[b];
    int KC = (ns + 31) & ~31;
    if (blockIdx.y >= 16) {
        int j0 = blockIdx.x * 64;
        if (j0 >= KC) return;
        int c0 = (blockIdx.y - 16) * 32;
        __shared__ unsigned short tt[64][34];
        const unsigned short* S = Ft + (size_t)b * Npx * Cch;
        const int* ji = jb + b * Npx;
        int col = threadIdx.x & 31, rr = threadIdx.x >> 5;
        for (int r = rr; r < 64; r += 8) {
            int j = j0 + r;
            int src = (j < ns) ? ji[j] : ji[0];   // pad cols: G==0 there
            tt[r][col] = S[(size_t)src * Cch + c0 + col];
        }
        __syncthreads();
        unsigned* D32 = (unsigned*)(Fg + (size_t)b * Cch * Npx);
        int jx = threadIdx.x & 31;
        for (int cr = rr; cr < 32; cr += 8) {
            unsigned lo = tt[2 * jx][cr], hi = tt[2 * jx + 1][cr];
            D32[(size_t)(c0 + cr) * (Npx / 2) + (j0 >> 1) + jx] = lo | (hi << 16);
        }
        return;
    }
    int j0 = blockIdx.y * 64;
    if (j0 >= KC) return;
    int i0 = blockIdx.x * 64;
    __shared__ unsigned short At[64][72];
    __shared__ unsigned short Bt[64][72];
    __shared__ int sji[64];
    __shared__ float sfi[64], sfj[64];
    const unsigned short* FA = Ft + (size_t)b * Npx * Cch;
    int tid = threadIdx.x;
    if (tid < 64) {
        int j = j0 + tid;
        sji[tid] = (j < ns) ? jb[b * Npx + j] : jb[b * Npx];
        sfj[tid] = (j < ns) ? ivg[b * Npx + j] : 0.f;
        sfi[tid] = 2.f * invn[b * Npx + i0 + tid];
    }
    __syncthreads();
    int rA = tid >> 2, kc8 = (tid & 3) * 8;
    const unsigned short* sa = FA + (size_t)(i0 + rA) * Cch + kc8;
    const unsigned short* sb = FA + (size_t)sji[rA] * Cch + kc8;
    int l = tid & 63, w = tid >> 6;
    int ml = l & 15, quad = l >> 4;
    f32x4 acc[4] = {};
    uint4 a0 = *(const uint4*)sa,        a1 = *(const uint4*)(sa + 32);
    uint4 b0 = *(const uint4*)sb,        b1 = *(const uint4*)(sb + 32);
    for (int k0 = 0; k0 < Cch; k0 += 64) {
        __syncthreads();
        *(uint4*)&At[rA][kc8] = a0;  *(uint4*)&At[rA][kc8 + 32] = a1;
        *(uint4*)&Bt[rA][kc8] = b0;  *(uint4*)&Bt[rA][kc8 + 32] = b1;
        __syncthreads();
        int kn = k0 + 64;
        if (kn < Cch) {
            a0 = *(const uint4*)(sa + kn);  a1 = *(const uint4*)(sa + kn + 32);
            b0 = *(const uint4*)(sb + kn);  b1 = *(const uint4*)(sb + kn + 32);
        }
        #pragma unroll
        for (int h = 0; h < 2; h++) {
            bf16x8 af = *(const bf16x8*)&At[w * 16 + ml][quad * 8 + h * 32];
            bf16x8 bfr[4];
            #pragma unroll
            for (int v = 0; v < 4; v++) bfr[v] = *(const bf16x8*)&Bt[v * 16 + ml][quad * 8 + h * 32];
            #pragma unroll
            for (int v = 0; v < 4; v++)
                acc[v] = __builtin_amdgcn_mfma_f32_16x16x32_bf16(af, bfr[v], acc[v], 0, 0, 0);
        }
    }
    unsigned short* g = G + (size_t)b * Npx * Npx;
    #pragma unroll
    for (int r = 0; r < 4; r++) {
        int il = w * 16 + quad * 4 + r;
        float fi = sfi[il];
        #pragma unroll
        for (int v = 0; v < 4; v++) {
            int jl = v * 16 + ml;
            float e = 0.f;
            if (j0 + jl < ns) e = __expf(acc[v][r] * fi * sfj[jl]);
            g[(size_t)(i0 + il) * Npx + j0 + jl] = f2bf(e);
        }
    }
}

// ---------------- 5: PV(64x64) + local denom + fused finalize ----------------
// grid (Npx/64, Cch/64, Bsz), block 256 (4 waves). K=64 staging.
// Row denominators computed from the staged G values (no gram dependency).
// Per-i partial sums (db, nb, df, qq) -> LDS -> global atomics.
// Last block of each batch finalizes that batch's output (k_fin folded in).
__global__ void __launch_bounds__(256) k_pv_c(const unsigned short* __restrict__ Fg,
                                              const unsigned short* __restrict__ A,
                                              const unsigned short* __restrict__ Ft,
                                              const int* __restrict__ nsb,
                                              const float* __restrict__ bgp,
                                              const float* __restrict__ FP1,
                                              float* __restrict__ accs,
                                              const float* __restrict__ nfv,
                                              int* __restrict__ wcnt,
                                              float* __restrict__ out) {
    int b = blockIdx.z;
    int KC64 = ((((nsb[b] + 31) & ~31) + 63) & ~63);   // G/Fg defined up to here
    __shared__ unsigned short At[64][72];
    __shared__ unsigned short Bt[64][72];
    __shared__ float sfp1[64], sbg[64], sden[64];
    __shared__ float spdb[64], spnb[64], spdf[64], spqq[64];
    int i0 = blockIdx.x * 64, c0 = blockIdx.y * 64;
    const unsigned short* F = Fg + (size_t)b * Cch * Npx;
    const unsigned short* Ar = A + (size_t)b * Npx * Npx;
    int tid = threadIdx.x;
    if (tid < 64) {
        sfp1[tid] = FP1[b * Cch + c0 + tid];
        sbg[tid] = 0.3f * bgp[b * Cch + c0 + tid];
    }
    int rr = tid >> 2, kc8 = (tid & 3) * 8;
    const unsigned short* sa = F + (size_t)(c0 + rr) * Npx + kc8;
    const unsigned short* sb = Ar + (size_t)(i0 + rr) * Npx + kc8;
    int l = tid & 63, w = tid >> 6;
    int ml = l & 15, quad = l >> 4;
    f32x4 acc[4] = {};
    float dsum = 0.f;                     // running sum of this thread's G values
    uint4 a0 = *(const uint4*)sa,  a1 = *(const uint4*)(sa + 32);
    uint4 b0 = *(const uint4*)sb,  b1 = *(const uint4*)(sb + 32);
    for (int j0 = 0; j0 < KC64; j0 += 64) {
        __syncthreads();
        *(uint4*)&At[rr][kc8] = a0;  *(uint4*)&At[rr][kc8 + 32] = a1;
        *(uint4*)&Bt[rr][kc8] = b0;  *(uint4*)&Bt[rr][kc8 + 32] = b1;
        // accumulate row-i0+rr partial denom from the 16 staged G bf16s
        dsum += __uint_as_float(b0.x << 16) + __uint_as_float(b0.x & 0xFFFF0000u)
              + __uint_as_float(b0.y << 16) + __uint_as_float(b0.y & 0xFFFF0000u)
              + __uint_as_float(b0.z << 16) + __uint_as_float(b0.z & 0xFFFF0000u)
              + __uint_as_float(b0.w << 16) + __uint_as_float(b0.w & 0xFFFF0000u)
              + __uint_as_float(b1.x << 16) + __uint_as_float(b1.x & 0xFFFF0000u)
              + __uint_as_float(b1.y << 16) + __uint_as_float(b1.y & 0xFFFF0000u)
              + __uint_as_float(b1.z << 16) + __uint_as_float(b1.z & 0xFFFF0000u)
              + __uint_as_float(b1.w << 16) + __uint_as_float(b1.w & 0xFFFF0000u);
        __syncthreads();
        int jn = j0 + 64;
        if (jn < KC64) {
            a0 = *(const uint4*)(sa + jn);  a1 = *(const uint4*)(sa + jn + 32);
            b0 = *(const uint4*)(sb + jn);  b1 = *(const uint4*)(sb + jn + 32);
        }
        #pragma unroll
        for (int h = 0; h < 2; h++) {
            bf16x8 af = *(const bf16x8*)&At[w * 16 + ml][quad * 8 + h * 32];
            bf16x8 bfr[4];
            #pragma unroll
            for (int v = 0; v < 4; v++) bfr[v] = *(const bf16x8*)&Bt[v * 16 + ml][quad * 8 + h * 32];
            #pragma unroll
            for (int v = 0; v < 4; v++)
                acc[v] = __builtin_amdgcn_mfma_f32_16x16x32_bf16(af, bfr[v], acc[v], 0, 0, 0);
        }
    }
    // combine denom partials across the 4 kc-threads of each row (same wave)
    dsum += __shfl_xor(dsum, 1);
    dsum += __shfl_xor(dsum, 2);
    if ((tid & 3) == 0) sden[rr] = dsum;
    // ---- epilogue: stage Ft tile [i0..+64)x[c0..+64) into At (reuse) ----
    __syncthreads();
    {
        const unsigned short* src = Ft + (size_t)b * Npx * Cch + (size_t)(i0 + (tid >> 2)) * Cch + c0 + (tid & 3) * 16;
        *(uint4*)&At[tid >> 2][(tid & 3) * 16] = *(const uint4*)src;
        *(uint4*)&At[tid >> 2][(tid & 3) * 16 + 8] = *(const uint4*)(src + 8);
    }
    if (tid < 64) { spdb[tid] = 0.f; spnb[tid] = 0.f; spdf[tid] = 0.f; spqq[tid] = 0.f; }
    float rd[4];
    #pragma unroll
    for (int v = 0; v < 4; v++) rd[v] = 1.f / sden[v * 16 + ml];
    __syncthreads();
    #pragma unroll
    for (int v = 0; v < 4; v++) {
        int iloc = v * 16 + ml;
        float sdb = 0.f, snb = 0.f, sdf = 0.f, sqq = 0.f;
        #pragma unroll
        for (int r = 0; r < 4; r++) {
            int cl = w * 16 + quad * 4 + r;
            float loc = acc[v][r] * rd[v];
            float bp1 = sbg[cl] + 0.7f * loc;
            float qv = bf2f(At[iloc][cl]);
            sdb += qv * bp1;
            snb += bp1 * bp1;
            sdf += qv * sfp1[cl];
            sqq += qv * qv;
        }
        #pragma unroll
        for (int m = 16; m < 64; m <<= 1) {
            sdb += __shfl_xor(sdb, m);
            snb += __shfl_xor(snb, m);
            sdf += __shfl_xor(sdf, m);
            sqq += __shfl_xor(sqq, m);
        }
        if (quad == 0) {
            atomicAdd(&spdb[iloc], sdb);
            atomicAdd(&spnb[iloc], snb);
            atomicAdd(&spdf[iloc], sdf);
            atomicAdd(&spqq[iloc], sqq);
        }
    }
    __syncthreads();
    {
        int a = tid >> 6, idx = tid & 63;
        float v = (a == 0) ? spdb[idx] : (a == 1) ? spnb[idx] : (a == 2) ? spdf[idx] : spqq[idx];
        // accs layout: [pdb, pnb, pdf, pqq] each BN floats
        atomicAdd(&accs[(size_t)a * BN + b * Npx + i0 + idx], v);
    }
    // ---- last block of this batch finalizes its 1024 pixels ----
    __syncthreads();
    __threadfence();
    __shared__ int lastF;
    if (tid == 0) lastF = (atomicAdd(&wcnt[b], 1) == (16 * 8 - 1)) ? 1 : 0;
    __syncthreads();
    if (lastF) {
        __threadfence();
        float nfb = nfv[b];
        for (int q = tid; q < Npx; q += 256) {
            int base = b * Npx + q;
            float db = accs[(size_t)0 * BN + base];
            float nb = accs[(size_t)1 * BN + base];
            float df = accs[(size_t)2 * BN + base];
            float qq = accs[(size_t)3 * BN + base];
            float nq = sqrtf(qq);
            float sf = 10.f * df / fmaxf(nq * nfb, 1e-8f);
            float sb2 = 10.f * db / fmaxf(nq * sqrtf(nb), 1e-8f);
            out[((size_t)b * 2) * Npx + q] = sb2;
            out[((size_t)b * 2 + 1) * Npx + q] = sf;
        }
    }
}

extern "C" void kernel_launch(void* const* d_in, const int* in_sizes, int n_in,
                              void* d_out, int out_size, void* d_ws, size_t ws_size,
                              hipStream_t stream) {
    const float* fq = (const float*)d_in[0];
    const float* sf = (const float*)d_in[1];
    const int* mask = (const int*)d_in[2];
    float* out = (float*)d_out;

    float* ws = (float*)d_ws;
    float* FP    = ws;                        // B*C
    float* BP    = FP + Bsz * Cch;
    float* fgp   = BP + Bsz * Cch;
    float* bgp   = fgp + Bsz * Cch;
    float* FP1   = bgp + Bsz * Cch;           // B*C
    float* nfv   = FP1 + Bsz * Cch;           // 8
    float* dsim  = nfv + 8;                   // B*N
    float* invn  = dsim + BN;
    float* ivg   = invn + BN;
    int*   nsf   = (int*)(ivg + BN);          // 8
    int*   nsb   = nsf + 8;                   // 8
    int*   jf    = nsb + 8;                   // B*N
    int*   jb    = jf + BN;                   // B*N
    float* accs  = (float*)(jb + BN);         // 4*B*N: pdb,pnb,pdf,pqq
    int*   wcnt  = (int*)(accs + (size_t)4 * BN);   // 8 counters
    unsigned short* Ft = (unsigned short*)(wcnt + 8);                    // 8 MB [i][c]
    unsigned short* Fg = Ft + (size_t)Bsz * Npx * Cch;                   // 8 MB [c][jc]
    unsigned short* Gb = Fg + (size_t)Bsz * Cch * Npx;                   // 16 MB

    k_pool<<<dim3(Cch, Bsz), 256, 0, stream>>>(sf, mask, FP, BP);
    k_predcast<<<dim3(Npx / 32, Bsz), 512, 0, stream>>>(fq, FP, BP, dsim, invn, Ft, accs, wcnt);
    k_selcompact<<<dim3(2, Bsz), 1024, 0, stream>>>(dsim, invn, Ft, FP, nsf, nsb, jf, jb, ivg, fgp, bgp, FP1, nfv);
    k_gram_fused<<<dim3(16, 32, Bsz), 256, 0, stream>>>(Ft, jb, nsb, invn, ivg, Gb, Fg);
    k_pv_c<<<dim3(Npx / 64, Cch / 64, Bsz), 256, 0, stream>>>(Fg, Gb, Ft, nsb, bgp, FP1, accs, nfv, wcnt, out);
}

// Round 7
// 132.707 us; speedup vs baseline: 1.4984x; 1.4984x over previous
//
#include <hip/hip_runtime.h>
#include <math.h>

#define Bsz 8
#define Cch 512
#define Npx 1024
#define TOPK 12
#define BN (Bsz * Npx)

typedef __attribute__((ext_vector_type(8))) short bf16x8;
typedef __attribute__((ext_vector_type(4))) float f32x4;

__device__ __forceinline__ unsigned short f2bf(float x) {
    unsigned u = __float_as_uint(x);
    u += 0x7FFF + ((u >> 16) & 1);
    return (unsigned short)(u >> 16);
}
__device__ __forceinline__ float bf2f(unsigned short h) {
    return __uint_as_float(((unsigned)h) << 16);
}

// ---------------- reduction helpers ----------------
__device__ __forceinline__ float warp_sum64(float v) {
    for (int o = 32; o > 0; o >>= 1) v += __shfl_down(v, o);
    return v;
}
__device__ __forceinline__ float block_sum512(float v, float* s8) {
    v = warp_sum64(v);
    int lane = threadIdx.x & 63, w = threadIdx.x >> 6;
    __syncthreads();
    if (lane == 0) s8[w] = v;
    __syncthreads();
    float r = 0.f;
    #pragma unroll
    for (int k = 0; k < 8; k++) r += s8[k];
    return r;
}

// ---------------- 1: masked average pool (float4, single-barrier) -------------
// grid (Cch, Bsz), block 256
__global__ void k_pool(const float* __restrict__ sf, const int* __restrict__ mask,
                       float* __restrict__ FPo, float* __restrict__ BPo) {
    __shared__ float s4a[4], s4b[4], s4c[4];
    int c = blockIdx.x, b = blockIdx.y, t = threadIdx.x;
    const float4* f4 = (const float4*)(sf + ((size_t)b * Cch + c) * Npx);
    const int4* m4 = (const int4*)(mask + (size_t)b * Npx);
    float4 v = f4[t];
    int4 m = m4[t];
    float sumf = (m.x == 1 ? v.x : 0.f) + (m.y == 1 ? v.y : 0.f)
               + (m.z == 1 ? v.z : 0.f) + (m.w == 1 ? v.w : 0.f);
    float tot = v.x + v.y + v.z + v.w;
    float cf = (float)((m.x == 1) + (m.y == 1) + (m.z == 1) + (m.w == 1));
    sumf = warp_sum64(sumf);
    tot  = warp_sum64(tot);
    cf   = warp_sum64(cf);
    int lane = t & 63, w = t >> 6;
    if (lane == 0) { s4a[w] = sumf; s4b[w] = tot; s4c[w] = cf; }
    __syncthreads();
    if (t == 0) {
        float sA = s4a[0] + s4a[1] + s4a[2] + s4a[3];
        float sB = s4b[0] + s4b[1] + s4b[2] + s4b[3];
        float sC = s4c[0] + s4c[1] + s4c[2] + s4c[3];
        FPo[b * Cch + c] = sA / (sC + 1e-5f);
        BPo[b * Cch + c] = (sB - sA) / ((1024.f - sC) + 1e-5f);
    }
}

// ---------------- 2: pred logit + bf16 cast (block 512: 16 thr/pixel) ---------
// grid (Npx/32, Bsz), block 512. Also zeroes the 4 accumulator arrays
// (pdb, pnb, pdf, pqq) consumed by PV atomics.
__global__ void __launch_bounds__(512) k_predcast(const float* __restrict__ fq,
                       const float* __restrict__ FP, const float* __restrict__ BP,
                       float* __restrict__ dsim, float* __restrict__ invn,
                       unsigned short* __restrict__ Ft, float* __restrict__ accs) {
    __shared__ float sFP[Cch], sBP[Cch], s8[8];
    __shared__ float rdf[16][32], rdb[16][32], rqq[16][32];
    __shared__ unsigned short S[32][522];   // odd dword stride -> conflict-free
    int b = blockIdx.y, t = threadIdx.x;
    int tx = t & 31, ty = t >> 5;           // ty in [0,16)
    int p0 = blockIdx.x * 32;
    int p = p0 + tx;
    if (t < 128) accs[(size_t)(t >> 5) * BN + b * Npx + p0 + (t & 31)] = 0.f;
    sFP[t] = FP[b * Cch + t];
    sBP[t] = BP[b * Cch + t];
    __syncthreads();
    float nf = sqrtf(block_sum512(sFP[t] * sFP[t], s8));
    float nb = sqrtf(block_sum512(sBP[t] * sBP[t], s8));
    const float* q = fq + (size_t)b * Cch * Npx + p;
    float df = 0.f, db = 0.f, qq = 0.f;
    int c0 = ty * 32;
    #pragma unroll 4
    for (int c = 0; c < 32; c += 2) {
        float v0 = q[(size_t)(c0 + c) * Npx];
        float v1 = q[(size_t)(c0 + c + 1) * Npx];
        df += v0 * sFP[c0 + c] + v1 * sFP[c0 + c + 1];
        db += v0 * sBP[c0 + c] + v1 * sBP[c0 + c + 1];
        qq += v0 * v0 + v1 * v1;
        unsigned pk = (unsigned)f2bf(v0) | ((unsigned)f2bf(v1) << 16);
        *(unsigned*)&S[tx][c0 + c] = pk;
    }
    rdf[ty][tx] = df; rdb[ty][tx] = db; rqq[ty][tx] = qq;
    __syncthreads();
    for (int s = 8; s > 0; s >>= 1) {
        if (ty < s) {
            rdf[ty][tx] += rdf[ty + s][tx];
            rdb[ty][tx] += rdb[ty + s][tx];
            rqq[ty][tx] += rqq[ty + s][tx];
        }
        __syncthreads();
    }
    if (ty == 0) {
        float nq = sqrtf(rqq[0][tx]);
        float simf = 10.f * rdf[0][tx] / fmaxf(nq * nf, 1e-8f);
        float simb = 10.f * rdb[0][tx] / fmaxf(nq * nb, 1e-8f);
        dsim[b * Npx + p] = simf - simb;
        invn[b * Npx + p] = 1.f / nq;
    }
    // write Ft rows (coalesced dword stores, conflict-free LDS dword reads)
    int w = t >> 6, lane = t & 63;           // 8 waves
    unsigned short* FtB = Ft + (size_t)b * Npx * Cch;
    for (int pr = w; pr < 32; pr += 8) {
        unsigned* dst = (unsigned*)(FtB + (size_t)(p0 + pr) * Cch);
        #pragma unroll
        for (int it = 0; it < 4; it++) {
            int d = it * 64 + lane;
            dst[d] = *(const unsigned*)&S[pr][d * 2];
        }
    }
}

// ---------------- 3: select + compact + prototypes + FP1/nf -------------------
// grid (2, Bsz), block 1024 (16 waves). x=0: fg, x=1: bg
__global__ void __launch_bounds__(1024) k_selcompact(const float* __restrict__ dsim,
                        const float* __restrict__ invn,
                        const unsigned short* __restrict__ Ft,
                        const float* __restrict__ FP,
                        int* __restrict__ nsf, int* __restrict__ nsb,
                        int* __restrict__ jf, int* __restrict__ jb,
                        float* __restrict__ ivg,
                        float* __restrict__ fgp, float* __restrict__ bgp,
                        float* __restrict__ FP1, float* __restrict__ nfv) {
    __shared__ int wsum[16];
    __shared__ int sns;
    __shared__ float sProto[16][512];       // 32 KB
    __shared__ float s16f[16];
    int b = blockIdx.y, t = threadIdx.x;
    int lane = t & 63, w = t >> 6;
    bool isf = (blockIdx.x == 0);
    float d = dsim[b * Npx + t];
    float key = isf ? d : -d;
    float thres = isf ? 0.8472979f : 0.4054651f;   // ln(0.7/0.3), ln(0.6/0.4)
    int flag = (key > thres) ? 1 : 0;
    int x = flag;
    #pragma unroll
    for (int o = 1; o < 64; o <<= 1) {
        int y = __shfl_up(x, o);
        if (lane >= o) x += y;
    }
    if (lane == 63) wsum[w] = x;
    __syncthreads();
    int base = 0, total = 0;
    #pragma unroll
    for (int k = 0; k < 16; k++) {
        int s = wsum[k];
        if (k < w) base += s;
        total += s;
    }
    int* jdst = (isf ? jf : jb) + b * Npx;
    if (total == 0) {
        // cold path: top-12 fallback (lower index wins ties)
        __shared__ int   sc[Npx];
        __shared__ float v[Npx];
        __shared__ float rv[Npx];
        __shared__ int   ri[Npx];
        v[t] = key; flag = 0;
        __syncthreads();
        for (int k = 0; k < TOPK; k++) {
            rv[t] = v[t]; ri[t] = t;
            __syncthreads();
            for (int s = 512; s > 0; s >>= 1) {
                if (t < s) {
                    float a = rv[t], bb = rv[t + s];
                    int ia = ri[t], ib = ri[t + s];
                    if (bb > a || (bb == a && ib < ia)) { rv[t] = bb; ri[t] = ib; }
                }
                __syncthreads();
            }
            int win = ri[0];
            if (t == win) { flag = 1; v[t] = -INFINITY; }
            __syncthreads();
        }
        sc[t] = flag;
        __syncthreads();
        for (int off = 1; off < 1024; off <<= 1) {
            int xx = (t >= off) ? sc[t - off] : 0;
            __syncthreads();
            sc[t] += xx;
            __syncthreads();
        }
        if (flag) {
            int pos = sc[t] - 1;
            jdst[pos] = t;
            if (!isf) ivg[b * Npx + pos] = invn[b * Npx + t];
        }
        if (t == 1023) sns = sc[1023];
    } else {
        if (flag) {
            int pos = base + x - 1;
            jdst[pos] = t;
            if (!isf) ivg[b * Npx + pos] = invn[b * Npx + t];
        }
        if (t == 0) sns = total;
    }
    __syncthreads();                         // jdst writes + sns visible to block
    int ns = sns;
    if (t == 0) (isf ? nsf : nsb)[b] = ns;
    // ---- prototype: mean of selected Ft rows (coalesced 1KB row reads) ----
    const unsigned short* FtB = Ft + (size_t)b * Npx * Cch;
    float facc[8] = {0.f, 0.f, 0.f, 0.f, 0.f, 0.f, 0.f, 0.f};
    int k = w;
    int row = (k < ns) ? jdst[k] : 0;
    while (k < ns) {
        int kn = k + 16;
        int rown = (kn < ns) ? jdst[kn] : 0;   // prefetch index
        bf16x8 vv = *(const bf16x8*)&FtB[(size_t)row * Cch + lane * 8];
        #pragma unroll
        for (int e = 0; e < 8; e++) facc[e] += bf2f((unsigned short)vv[e]);
        k = kn; row = rown;
    }
    #pragma unroll
    for (int e = 0; e < 8; e++) sProto[w][lane * 8 + e] = facc[e];
    __syncthreads();
    float fp1 = 0.f;
    if (t < 512) {
        float s = 0.f;
        #pragma unroll
        for (int q = 0; q < 16; q++) s += sProto[q][t];
        float pv = s / (float)ns;
        (isf ? fgp : bgp)[b * Cch + t] = pv;
        if (isf) {
            fp1 = 0.5f * FP[b * Cch + t] + 0.5f * pv;
            FP1[b * Cch + t] = fp1;
        }
    }
    if (isf) {
        // ||FP1|| for the final fg similarity
        float v2 = warp_sum64(fp1 * fp1);
        if (lane == 0) s16f[w] = v2;
        __syncthreads();
        if (t == 0) {
            float nn = 0.f;
            #pragma unroll
            for (int q = 0; q < 16; q++) nn += s16f[q];
            nfv[b] = sqrtf(nn);
        }
    }
}

// ---------------- 4: Gram(64x64)+exp  ||  gather-transpose Fg -----------------
// grid (16, 32, Bsz), block 256 (4 waves). K=64 staging.
//   y in [0,16):  gram tile i0=x*64, j0=y*64 -> G=exp(sim) bf16 (0 for j>=ns)
//   y in [16,32): transpose tile c0=(y-16)*32, j0=x*64 -> Fg[c][j]
// (denominator computed inside PV -- no reduction/atomics here)
__global__ void __launch_bounds__(256) k_gram_fused(const unsigned short* __restrict__ Ft,
                        const int* __restrict__ jb, const int* __restrict__ nsb,
                        const float* __restrict__ invn, const float* __restrict__ ivg,
                        unsigned short* __restrict__ G, unsigned short* __restrict__ Fg) {
    int b = blockIdx.z;
    int ns = nsb[b];
    int KC = (ns + 31) & ~31;
    if (blockIdx.y >= 16) {
        int j0 = blockIdx.x * 64;
        if (j0 >= KC) return;
        int c0 = (blockIdx.y - 16) * 32;
        __shared__ unsigned short tt[64][34];
        const unsigned short* S = Ft + (size_t)b * Npx * Cch;
        const int* ji = jb + b * Npx;
        int col = threadIdx.x & 31, rr = threadIdx.x >> 5;
        for (int r = rr; r < 64; r += 8) {
            int j = j0 + r;
            int src = (j < ns) ? ji[j] : ji[0];   // pad cols: G==0 there
            tt[r][col] = S[(size_t)src * Cch + c0 + col];
        }
        __syncthreads();
        unsigned* D32 = (unsigned*)(Fg + (size_t)b * Cch * Npx);
        int jx = threadIdx.x & 31;
        for (int cr = rr; cr < 32; cr += 8) {
            unsigned lo = tt[2 * jx][cr], hi = tt[2 * jx + 1][cr];
            D32[(size_t)(c0 + cr) * (Npx / 2) + (j0 >> 1) + jx] = lo | (hi << 16);
        }
        return;
    }
    int j0 = blockIdx.y * 64;
    if (j0 >= KC) return;
    int i0 = blockIdx.x * 64;
    __shared__ unsigned short At[64][72];
    __shared__ unsigned short Bt[64][72];
    __shared__ int sji[64];
    __shared__ float sfi[64], sfj[64];
    const unsigned short* FA = Ft + (size_t)b * Npx * Cch;
    int tid = threadIdx.x;
    if (tid < 64) {
        int j = j0 + tid;
        sji[tid] = (j < ns) ? jb[b * Npx + j] : jb[b * Npx];
        sfj[tid] = (j < ns) ? ivg[b * Npx + j] : 0.f;
        sfi[tid] = 2.f * invn[b * Npx + i0 + tid];
    }
    __syncthreads();
    int rA = tid >> 2, kc8 = (tid & 3) * 8;
    const unsigned short* sa = FA + (size_t)(i0 + rA) * Cch + kc8;
    const unsigned short* sb = FA + (size_t)sji[rA] * Cch + kc8;
    int l = tid & 63, w = tid >> 6;
    int ml = l & 15, quad = l >> 4;
    f32x4 acc[4] = {};
    uint4 a0 = *(const uint4*)sa,        a1 = *(const uint4*)(sa + 32);
    uint4 b0 = *(const uint4*)sb,        b1 = *(const uint4*)(sb + 32);
    for (int k0 = 0; k0 < Cch; k0 += 64) {
        __syncthreads();
        *(uint4*)&At[rA][kc8] = a0;  *(uint4*)&At[rA][kc8 + 32] = a1;
        *(uint4*)&Bt[rA][kc8] = b0;  *(uint4*)&Bt[rA][kc8 + 32] = b1;
        __syncthreads();
        int kn = k0 + 64;
        if (kn < Cch) {
            a0 = *(const uint4*)(sa + kn);  a1 = *(const uint4*)(sa + kn + 32);
            b0 = *(const uint4*)(sb + kn);  b1 = *(const uint4*)(sb + kn + 32);
        }
        #pragma unroll
        for (int h = 0; h < 2; h++) {
            bf16x8 af = *(const bf16x8*)&At[w * 16 + ml][quad * 8 + h * 32];
            bf16x8 bfr[4];
            #pragma unroll
            for (int v = 0; v < 4; v++) bfr[v] = *(const bf16x8*)&Bt[v * 16 + ml][quad * 8 + h * 32];
            #pragma unroll
            for (int v = 0; v < 4; v++)
                acc[v] = __builtin_amdgcn_mfma_f32_16x16x32_bf16(af, bfr[v], acc[v], 0, 0, 0);
        }
    }
    unsigned short* g = G + (size_t)b * Npx * Npx;
    #pragma unroll
    for (int r = 0; r < 4; r++) {
        int il = w * 16 + quad * 4 + r;
        float fi = sfi[il];
        #pragma unroll
        for (int v = 0; v < 4; v++) {
            int jl = v * 16 + ml;
            float e = 0.f;
            if (j0 + jl < ns) e = __expf(acc[v][r] * fi * sfj[jl]);
            g[(size_t)(i0 + il) * Npx + j0 + jl] = f2bf(e);
        }
    }
}

// ---------------- 5: PV(64x64) + local denom + fused similarity partials ------
// grid (Npx/64, Cch/64, Bsz), block 256 (4 waves). K=64 staging.
// Row denominators computed from the staged G values (no gram dependency).
// Per-i partial sums (db, nb, df, qq) -> LDS -> global atomics.
// NO threadfence / fused finalize: the whole-L2 wb/inv per block thrashed L2
// (R6: 95us, MfmaUtil 1%). Separate k_fin launch relies on kernel-boundary
// coherence instead.
__global__ void __launch_bounds__(256) k_pv_c(const unsigned short* __restrict__ Fg,
                                              const unsigned short* __restrict__ A,
                                              const unsigned short* __restrict__ Ft,
                                              const int* __restrict__ nsb,
                                              const float* __restrict__ bgp,
                                              const float* __restrict__ FP1,
                                              float* __restrict__ accs) {
    int b = blockIdx.z;
    int KC64 = ((((nsb[b] + 31) & ~31) + 63) & ~63);   // G/Fg defined up to here
    __shared__ unsigned short At[64][72];
    __shared__ unsigned short Bt[64][72];
    __shared__ float sfp1[64], sbg[64], sden[64];
    __shared__ float spdb[64], spnb[64], spdf[64], spqq[64];
    int i0 = blockIdx.x * 64, c0 = blockIdx.y * 64;
    const unsigned short* F = Fg + (size_t)b * Cch * Npx;
    const unsigned short* Ar = A + (size_t)b * Npx * Npx;
    int tid = threadIdx.x;
    if (tid < 64) {
        sfp1[tid] = FP1[b * Cch + c0 + tid];
        sbg[tid] = 0.3f * bgp[b * Cch + c0 + tid];
    }
    int rr = tid >> 2, kc8 = (tid & 3) * 8;
    const unsigned short* sa = F + (size_t)(c0 + rr) * Npx + kc8;
    const unsigned short* sb = Ar + (size_t)(i0 + rr) * Npx + kc8;
    int l = tid & 63, w = tid >> 6;
    int ml = l & 15, quad = l >> 4;
    f32x4 acc[4] = {};
    float dsum = 0.f;                     // running sum of this thread's G values
    uint4 a0 = *(const uint4*)sa,  a1 = *(const uint4*)(sa + 32);
    uint4 b0 = *(const uint4*)sb,  b1 = *(const uint4*)(sb + 32);
    for (int j0 = 0; j0 < KC64; j0 += 64) {
        __syncthreads();
        *(uint4*)&At[rr][kc8] = a0;  *(uint4*)&At[rr][kc8 + 32] = a1;
        *(uint4*)&Bt[rr][kc8] = b0;  *(uint4*)&Bt[rr][kc8 + 32] = b1;
        // accumulate row-i0+rr partial denom from the 16 staged G bf16s
        dsum += __uint_as_float(b0.x << 16) + __uint_as_float(b0.x & 0xFFFF0000u)
              + __uint_as_float(b0.y << 16) + __uint_as_float(b0.y & 0xFFFF0000u)
              + __uint_as_float(b0.z << 16) + __uint_as_float(b0.z & 0xFFFF0000u)
              + __uint_as_float(b0.w << 16) + __uint_as_float(b0.w & 0xFFFF0000u)
              + __uint_as_float(b1.x << 16) + __uint_as_float(b1.x & 0xFFFF0000u)
              + __uint_as_float(b1.y << 16) + __uint_as_float(b1.y & 0xFFFF0000u)
              + __uint_as_float(b1.z << 16) + __uint_as_float(b1.z & 0xFFFF0000u)
              + __uint_as_float(b1.w << 16) + __uint_as_float(b1.w & 0xFFFF0000u);
        __syncthreads();
        int jn = j0 + 64;
        if (jn < KC64) {
            a0 = *(const uint4*)(sa + jn);  a1 = *(const uint4*)(sa + jn + 32);
            b0 = *(const uint4*)(sb + jn);  b1 = *(const uint4*)(sb + jn + 32);
        }
        #pragma unroll
        for (int h = 0; h < 2; h++) {
            bf16x8 af = *(const bf16x8*)&At[w * 16 + ml][quad * 8 + h * 32];
            bf16x8 bfr[4];
            #pragma unroll
            for (int v = 0; v < 4; v++) bfr[v] = *(const bf16x8*)&Bt[v * 16 + ml][quad * 8 + h * 32];
            #pragma unroll
            for (int v = 0; v < 4; v++)
                acc[v] = __builtin_amdgcn_mfma_f32_16x16x32_bf16(af, bfr[v], acc[v], 0, 0, 0);
        }
    }
    // combine denom partials across the 4 kc-threads of each row (same wave)
    dsum += __shfl_xor(dsum, 1);
    dsum += __shfl_xor(dsum, 2);
    if ((tid & 3) == 0) sden[rr] = dsum;
    // ---- epilogue: stage Ft tile [i0..+64)x[c0..+64) into At (reuse) ----
    __syncthreads();
    {
        const unsigned short* src = Ft + (size_t)b * Npx * Cch + (size_t)(i0 + (tid >> 2)) * Cch + c0 + (tid & 3) * 16;
        *(uint4*)&At[tid >> 2][(tid & 3) * 16] = *(const uint4*)src;
        *(uint4*)&At[tid >> 2][(tid & 3) * 16 + 8] = *(const uint4*)(src + 8);
    }
    if (tid < 64) { spdb[tid] = 0.f; spnb[tid] = 0.f; spdf[tid] = 0.f; spqq[tid] = 0.f; }
    float rd[4];
    #pragma unroll
    for (int v = 0; v < 4; v++) rd[v] = 1.f / sden[v * 16 + ml];
    __syncthreads();
    #pragma unroll
    for (int v = 0; v < 4; v++) {
        int iloc = v * 16 + ml;
        float sdb = 0.f, snb = 0.f, sdf = 0.f, sqq = 0.f;
        #pragma unroll
        for (int r = 0; r < 4; r++) {
            int cl = w * 16 + quad * 4 + r;
            float loc = acc[v][r] * rd[v];
            float bp1 = sbg[cl] + 0.7f * loc;
            float qv = bf2f(At[iloc][cl]);
            sdb += qv * bp1;
            snb += bp1 * bp1;
            sdf += qv * sfp1[cl];
            sqq += qv * qv;
        }
        #pragma unroll
        for (int m = 16; m < 64; m <<= 1) {
            sdb += __shfl_xor(sdb, m);
            snb += __shfl_xor(snb, m);
            sdf += __shfl_xor(sdf, m);
            sqq += __shfl_xor(sqq, m);
        }
        if (quad == 0) {
            atomicAdd(&spdb[iloc], sdb);
            atomicAdd(&spnb[iloc], snb);
            atomicAdd(&spdf[iloc], sdf);
            atomicAdd(&spqq[iloc], sqq);
        }
    }
    __syncthreads();
    {
        int a = tid >> 6, idx = tid & 63;
        float v = (a == 0) ? spdb[idx] : (a == 1) ? spnb[idx] : (a == 2) ? spdf[idx] : spqq[idx];
        // accs layout: [pdb, pnb, pdf, pqq] each BN floats
        atomicAdd(&accs[(size_t)a * BN + b * Npx + i0 + idx], v);
    }
}

// ---------------- 6: trivial per-pixel finalize ----------------
// grid (Npx/256, Bsz), block 256
__global__ void k_fin(const float* __restrict__ accs, const float* __restrict__ nfv,
                      float* __restrict__ out) {
    int b = blockIdx.y;
    int p = blockIdx.x * 256 + threadIdx.x;
    int base = b * Npx + p;
    float db = accs[(size_t)0 * BN + base];
    float nb = accs[(size_t)1 * BN + base];
    float df = accs[(size_t)2 * BN + base];
    float qq = accs[(size_t)3 * BN + base];
    float nq = sqrtf(qq);
    float sf = 10.f * df / fmaxf(nq * nfv[b], 1e-8f);
    float sb = 10.f * db / fmaxf(nq * sqrtf(nb), 1e-8f);
    out[((size_t)b * 2) * Npx + p] = sb;
    out[((size_t)b * 2 + 1) * Npx + p] = sf;
}

extern "C" void kernel_launch(void* const* d_in, const int* in_sizes, int n_in,
                              void* d_out, int out_size, void* d_ws, size_t ws_size,
                              hipStream_t stream) {
    const float* fq = (const float*)d_in[0];
    const float* sf = (const float*)d_in[1];
    const int* mask = (const int*)d_in[2];
    float* out = (float*)d_out;

    float* ws = (float*)d_ws;
    float* FP    = ws;                        // B*C
    float* BP    = FP + Bsz * Cch;
    float* fgp   = BP + Bsz * Cch;
    float* bgp   = fgp + Bsz * Cch;
    float* FP1   = bgp + Bsz * Cch;           // B*C
    float* nfv   = FP1 + Bsz * Cch;           // 8
    float* dsim  = nfv + 8;                   // B*N
    float* invn  = dsim + BN;
    float* ivg   = invn + BN;
    int*   nsf   = (int*)(ivg + BN);          // 8
    int*   nsb   = nsf + 8;                   // 8
    int*   jf    = nsb + 8;                   // B*N
    int*   jb    = jf + BN;                   // B*N
    float* accs  = (float*)(jb + BN);         // 4*B*N: pdb,pnb,pdf,pqq
    unsigned short* Ft = (unsigned short*)(accs + (size_t)4 * BN);       // 8 MB [i][c]
    unsigned short* Fg = Ft + (size_t)Bsz * Npx * Cch;                   // 8 MB [c][jc]
    unsigned short* Gb = Fg + (size_t)Bsz * Cch * Npx;                   // 16 MB

    k_pool<<<dim3(Cch, Bsz), 256, 0, stream>>>(sf, mask, FP, BP);
    k_predcast<<<dim3(Npx / 32, Bsz), 512, 0, stream>>>(fq, FP, BP, dsim, invn, Ft, accs);
    k_selcompact<<<dim3(2, Bsz), 1024, 0, stream>>>(dsim, invn, Ft, FP, nsf, nsb, jf, jb, ivg, fgp, bgp, FP1, nfv);
    k_gram_fused<<<dim3(16, 32, Bsz), 256, 0, stream>>>(Ft, jb, nsb, invn, ivg, Gb, Fg);
    k_pv_c<<<dim3(Npx / 64, Cch / 64, Bsz), 256, 0, stream>>>(Fg, Gb, Ft, nsb, bgp, FP1, accs);
    k_fin<<<dim3(Npx / 256, Bsz), 256, 0, stream>>>(accs, nfv, out);
}

// Round 8
// 130.563 us; speedup vs baseline: 1.5230x; 1.0164x over previous
//
#include <hip/hip_runtime.h>
#include <math.h>

#define Bsz 8
#define Cch 512
#define Npx 1024
#define TOPK 12
#define BN (Bsz * Npx)

typedef __attribute__((ext_vector_type(8))) short bf16x8;
typedef __attribute__((ext_vector_type(4))) float f32x4;

__device__ __forceinline__ unsigned short f2bf(float x) {
    unsigned u = __float_as_uint(x);
    u += 0x7FFF + ((u >> 16) & 1);
    return (unsigned short)(u >> 16);
}
__device__ __forceinline__ float bf2f(unsigned short h) {
    return __uint_as_float(((unsigned)h) << 16);
}

// ---------------- reduction helpers ----------------
__device__ __forceinline__ float warp_sum64(float v) {
    for (int o = 32; o > 0; o >>= 1) v += __shfl_down(v, o);
    return v;
}
__device__ __forceinline__ float block_sum512(float v, float* s8) {
    v = warp_sum64(v);
    int lane = threadIdx.x & 63, w = threadIdx.x >> 6;
    __syncthreads();
    if (lane == 0) s8[w] = v;
    __syncthreads();
    float r = 0.f;
    #pragma unroll
    for (int k = 0; k < 8; k++) r += s8[k];
    return r;
}

// ---------------- 1: masked average pool (float4, single-barrier) -------------
// grid (Cch, Bsz), block 256
__global__ void k_pool(const float* __restrict__ sf, const int* __restrict__ mask,
                       float* __restrict__ FPo, float* __restrict__ BPo) {
    __shared__ float s4a[4], s4b[4], s4c[4];
    int c = blockIdx.x, b = blockIdx.y, t = threadIdx.x;
    const float4* f4 = (const float4*)(sf + ((size_t)b * Cch + c) * Npx);
    const int4* m4 = (const int4*)(mask + (size_t)b * Npx);
    float4 v = f4[t];
    int4 m = m4[t];
    float sumf = (m.x == 1 ? v.x : 0.f) + (m.y == 1 ? v.y : 0.f)
               + (m.z == 1 ? v.z : 0.f) + (m.w == 1 ? v.w : 0.f);
    float tot = v.x + v.y + v.z + v.w;
    float cf = (float)((m.x == 1) + (m.y == 1) + (m.z == 1) + (m.w == 1));
    sumf = warp_sum64(sumf);
    tot  = warp_sum64(tot);
    cf   = warp_sum64(cf);
    int lane = t & 63, w = t >> 6;
    if (lane == 0) { s4a[w] = sumf; s4b[w] = tot; s4c[w] = cf; }
    __syncthreads();
    if (t == 0) {
        float sA = s4a[0] + s4a[1] + s4a[2] + s4a[3];
        float sB = s4b[0] + s4b[1] + s4b[2] + s4b[3];
        float sC = s4c[0] + s4c[1] + s4c[2] + s4c[3];
        FPo[b * Cch + c] = sA / (sC + 1e-5f);
        BPo[b * Cch + c] = (sB - sA) / ((1024.f - sC) + 1e-5f);
    }
}

// ---------------- 2: pred logit + bf16 cast (block 512: 16 thr/pixel) ---------
// grid (Npx/32, Bsz), block 512.
__global__ void __launch_bounds__(512) k_predcast(const float* __restrict__ fq,
                       const float* __restrict__ FP, const float* __restrict__ BP,
                       float* __restrict__ dsim, float* __restrict__ invn,
                       unsigned short* __restrict__ Ft) {
    __shared__ float sFP[Cch], sBP[Cch], s8[8];
    __shared__ float rdf[16][32], rdb[16][32], rqq[16][32];
    __shared__ unsigned short S[32][522];   // odd dword stride -> conflict-free
    int b = blockIdx.y, t = threadIdx.x;
    int tx = t & 31, ty = t >> 5;           // ty in [0,16)
    int p0 = blockIdx.x * 32;
    int p = p0 + tx;
    sFP[t] = FP[b * Cch + t];
    sBP[t] = BP[b * Cch + t];
    __syncthreads();
    float nf = sqrtf(block_sum512(sFP[t] * sFP[t], s8));
    float nb = sqrtf(block_sum512(sBP[t] * sBP[t], s8));
    const float* q = fq + (size_t)b * Cch * Npx + p;
    float df = 0.f, db = 0.f, qq = 0.f;
    int c0 = ty * 32;
    #pragma unroll 4
    for (int c = 0; c < 32; c += 2) {
        float v0 = q[(size_t)(c0 + c) * Npx];
        float v1 = q[(size_t)(c0 + c + 1) * Npx];
        df += v0 * sFP[c0 + c] + v1 * sFP[c0 + c + 1];
        db += v0 * sBP[c0 + c] + v1 * sBP[c0 + c + 1];
        qq += v0 * v0 + v1 * v1;
        unsigned pk = (unsigned)f2bf(v0) | ((unsigned)f2bf(v1) << 16);
        *(unsigned*)&S[tx][c0 + c] = pk;
    }
    rdf[ty][tx] = df; rdb[ty][tx] = db; rqq[ty][tx] = qq;
    __syncthreads();
    for (int s = 8; s > 0; s >>= 1) {
        if (ty < s) {
            rdf[ty][tx] += rdf[ty + s][tx];
            rdb[ty][tx] += rdb[ty + s][tx];
            rqq[ty][tx] += rqq[ty + s][tx];
        }
        __syncthreads();
    }
    if (ty == 0) {
        float nq = sqrtf(rqq[0][tx]);
        float simf = 10.f * rdf[0][tx] / fmaxf(nq * nf, 1e-8f);
        float simb = 10.f * rdb[0][tx] / fmaxf(nq * nb, 1e-8f);
        dsim[b * Npx + p] = simf - simb;
        invn[b * Npx + p] = 1.f / nq;
    }
    // write Ft rows (coalesced dword stores, conflict-free LDS dword reads)
    int w = t >> 6, lane = t & 63;           // 8 waves
    unsigned short* FtB = Ft + (size_t)b * Npx * Cch;
    for (int pr = w; pr < 32; pr += 8) {
        unsigned* dst = (unsigned*)(FtB + (size_t)(p0 + pr) * Cch);
        #pragma unroll
        for (int it = 0; it < 4; it++) {
            int d = it * 64 + lane;
            dst[d] = *(const unsigned*)&S[pr][d * 2];
        }
    }
}

// ---------------- 3: select + compact + prototypes + FP1/nf -------------------
// grid (2, Bsz), block 1024 (16 waves). x=0: fg, x=1: bg
__global__ void __launch_bounds__(1024) k_selcompact(const float* __restrict__ dsim,
                        const float* __restrict__ invn,
                        const unsigned short* __restrict__ Ft,
                        const float* __restrict__ FP,
                        int* __restrict__ nsf, int* __restrict__ nsb,
                        int* __restrict__ jf, int* __restrict__ jb,
                        float* __restrict__ ivg,
                        float* __restrict__ fgp, float* __restrict__ bgp,
                        float* __restrict__ FP1, float* __restrict__ nfv) {
    __shared__ int wsum[16];
    __shared__ int sns;
    __shared__ float sProto[16][512];       // 32 KB
    __shared__ float s16f[16];
    int b = blockIdx.y, t = threadIdx.x;
    int lane = t & 63, w = t >> 6;
    bool isf = (blockIdx.x == 0);
    float d = dsim[b * Npx + t];
    float key = isf ? d : -d;
    float thres = isf ? 0.8472979f : 0.4054651f;   // ln(0.7/0.3), ln(0.6/0.4)
    int flag = (key > thres) ? 1 : 0;
    int x = flag;
    #pragma unroll
    for (int o = 1; o < 64; o <<= 1) {
        int y = __shfl_up(x, o);
        if (lane >= o) x += y;
    }
    if (lane == 63) wsum[w] = x;
    __syncthreads();
    int base = 0, total = 0;
    #pragma unroll
    for (int k = 0; k < 16; k++) {
        int s = wsum[k];
        if (k < w) base += s;
        total += s;
    }
    int* jdst = (isf ? jf : jb) + b * Npx;
    if (total == 0) {
        // cold path: top-12 fallback (lower index wins ties)
        __shared__ int   sc[Npx];
        __shared__ float v[Npx];
        __shared__ float rv[Npx];
        __shared__ int   ri[Npx];
        v[t] = key; flag = 0;
        __syncthreads();
        for (int k = 0; k < TOPK; k++) {
            rv[t] = v[t]; ri[t] = t;
            __syncthreads();
            for (int s = 512; s > 0; s >>= 1) {
                if (t < s) {
                    float a = rv[t], bb = rv[t + s];
                    int ia = ri[t], ib = ri[t + s];
                    if (bb > a || (bb == a && ib < ia)) { rv[t] = bb; ri[t] = ib; }
                }
                __syncthreads();
            }
            int win = ri[0];
            if (t == win) { flag = 1; v[t] = -INFINITY; }
            __syncthreads();
        }
        sc[t] = flag;
        __syncthreads();
        for (int off = 1; off < 1024; off <<= 1) {
            int xx = (t >= off) ? sc[t - off] : 0;
            __syncthreads();
            sc[t] += xx;
            __syncthreads();
        }
        if (flag) {
            int pos = sc[t] - 1;
            jdst[pos] = t;
            if (!isf) ivg[b * Npx + pos] = invn[b * Npx + t];
        }
        if (t == 1023) sns = sc[1023];
    } else {
        if (flag) {
            int pos = base + x - 1;
            jdst[pos] = t;
            if (!isf) ivg[b * Npx + pos] = invn[b * Npx + t];
        }
        if (t == 0) sns = total;
    }
    __syncthreads();                         // jdst writes + sns visible to block
    int ns = sns;
    if (t == 0) (isf ? nsf : nsb)[b] = ns;
    // ---- prototype: mean of selected Ft rows (coalesced 1KB row reads) ----
    const unsigned short* FtB = Ft + (size_t)b * Npx * Cch;
    float facc[8] = {0.f, 0.f, 0.f, 0.f, 0.f, 0.f, 0.f, 0.f};
    int k = w;
    int row = (k < ns) ? jdst[k] : 0;
    while (k < ns) {
        int kn = k + 16;
        int rown = (kn < ns) ? jdst[kn] : 0;   // prefetch index
        bf16x8 vv = *(const bf16x8*)&FtB[(size_t)row * Cch + lane * 8];
        #pragma unroll
        for (int e = 0; e < 8; e++) facc[e] += bf2f((unsigned short)vv[e]);
        k = kn; row = rown;
    }
    #pragma unroll
    for (int e = 0; e < 8; e++) sProto[w][lane * 8 + e] = facc[e];
    __syncthreads();
    float fp1 = 0.f;
    if (t < 512) {
        float s = 0.f;
        #pragma unroll
        for (int q = 0; q < 16; q++) s += sProto[q][t];
        float pv = s / (float)ns;
        (isf ? fgp : bgp)[b * Cch + t] = pv;
        if (isf) {
            fp1 = 0.5f * FP[b * Cch + t] + 0.5f * pv;
            FP1[b * Cch + t] = fp1;
        }
    }
    if (isf) {
        // ||FP1|| for the final fg similarity
        float v2 = warp_sum64(fp1 * fp1);
        if (lane == 0) s16f[w] = v2;
        __syncthreads();
        if (t == 0) {
            float nn = 0.f;
            #pragma unroll
            for (int q = 0; q < 16; q++) nn += s16f[q];
            nfv[b] = sqrtf(nn);
        }
    }
}

// ---------------- 4: FUSED gram + softmax + PV + finalize --------------------
// grid (32, Bsz) = 256 blocks (1/CU), block 512 (8 waves), ~123 KB LDS.
// Block owns i-rows [i0, i0+32): computes P = exp(sim) fully in LDS (no G/Fg
// in global), then PV over all c with in-block gather-transpose of V, then
// per-i similarity partials reduced in-block and final out written directly.
// Handles any ns up to 1024 (sP sized for KC64 = 1024).
__global__ void __launch_bounds__(512) k_fused(
        const unsigned short* __restrict__ Ft,
        const int* __restrict__ jb, const int* __restrict__ nsb,
        const float* __restrict__ invn, const float* __restrict__ ivg,
        const float* __restrict__ bgp, const float* __restrict__ FP1,
        const float* __restrict__ nfv, float* __restrict__ out) {
    __shared__ unsigned short Afull[32][520];   // q rows, full K (33.3 KB)
    __shared__ unsigned short sP[32][1032];     // attention rows (66 KB)
    __shared__ unsigned short Bt[64][136];      // gram-B / V-transpose staging (17.4 KB)
    __shared__ int   sji[1024];
    __shared__ float sfj[1024];
    __shared__ float sfi[32], sden[32];
    __shared__ float sfp1c[64], sbgc[64];
    __shared__ float spart[32][4];

    int b = blockIdx.y;
    int i0 = blockIdx.x * 32;
    int tid = threadIdx.x;
    int l = tid & 63, w = tid >> 6;
    int ml = l & 15, quad = l >> 4;
    int ns = nsb[b];
    int K64 = ((((ns + 31) & ~31) + 63) & ~63);

    const unsigned short* FtB = Ft + (size_t)b * Npx * Cch;

    // ---- stage A (q rows, full K) + index/scale tables ----
    #pragma unroll
    for (int s = 0; s < 4; s++) {
        int idx = tid + s * 512;
        int row = idx >> 6, kc8 = (idx & 63) * 8;
        *(uint4*)&Afull[row][kc8] = *(const uint4*)(FtB + (size_t)(i0 + row) * Cch + kc8);
    }
    for (int j = tid; j < K64; j += 512) {
        sji[j] = (j < ns) ? jb[b * Npx + j] : jb[b * Npx];
        sfj[j] = (j < ns) ? ivg[b * Npx + j] : 0.f;
    }
    if (tid < 32) sfi[tid] = 2.f * invn[b * Npx + i0 + tid];
    __syncthreads();

    // ---- phase 1: gram rows -> sP = exp(sim) (bf16) ----
    int ig = w & 1, jg = w >> 1;            // 8 waves tile 32i x 64j
    for (int j0 = 0; j0 < K64; j0 += 64) {
        const unsigned short* pb0 = FtB + (size_t)sji[j0 + (tid >> 4)] * Cch + (tid & 15) * 8;
        const unsigned short* pb1 = FtB + (size_t)sji[j0 + 32 + (tid >> 4)] * Cch + (tid & 15) * 8;
        uint4 v0 = *(const uint4*)pb0;
        uint4 v1 = *(const uint4*)pb1;
        f32x4 acc = {};
        for (int k0 = 0; k0 < Cch; k0 += 128) {
            __syncthreads();
            *(uint4*)&Bt[tid >> 4][(tid & 15) * 8] = v0;
            *(uint4*)&Bt[32 + (tid >> 4)][(tid & 15) * 8] = v1;
            __syncthreads();
            int kn = k0 + 128;
            if (kn < Cch) {
                v0 = *(const uint4*)(pb0 + kn);
                v1 = *(const uint4*)(pb1 + kn);
            }
            #pragma unroll
            for (int h = 0; h < 4; h++) {
                bf16x8 af = *(const bf16x8*)&Afull[ig * 16 + ml][k0 + h * 32 + quad * 8];
                bf16x8 bf = *(const bf16x8*)&Bt[jg * 16 + ml][h * 32 + quad * 8];
                acc = __builtin_amdgcn_mfma_f32_16x16x32_bf16(af, bf, acc, 0, 0, 0);
            }
        }
        #pragma unroll
        for (int r = 0; r < 4; r++) {
            int il = ig * 16 + quad * 4 + r;
            int jl = jg * 16 + ml;
            float e = (j0 + jl < ns) ? __expf(acc[r] * sfi[il] * sfj[j0 + jl]) : 0.f;
            sP[il][j0 + jl] = f2bf(e);
        }
    }
    __syncthreads();

    // ---- row denominators from sP + zero partial sums ----
    {
        int i = tid >> 4, jj16 = tid & 15;
        float s = 0.f;
        for (int j = jj16; j < K64; j += 16) s += bf2f(sP[i][j]);
        #pragma unroll
        for (int m = 1; m < 16; m <<= 1) s += __shfl_xor(s, m);
        if (jj16 == 0) sden[i] = s;
    }
    if (tid < 128) ((float*)spart)[tid] = 0.f;
    __syncthreads();

    // ---- phase 2: PV over all c + similarity partials ----
    int cgw = w & 3, igw = w >> 2;
    int icol = igw * 16 + ml;               // local i this lane accumulates
    float rdi = 1.f / sden[icol];
    float sdb = 0.f, snb = 0.f, sdf = 0.f, sqq = 0.f;
    int jj = tid & 63, cg = tid >> 6;
    for (int c0 = 0; c0 < Cch; c0 += 64) {
        __syncthreads();                    // protect sfp1c/sbgc + Bt reuse
        if (tid < 64) {
            sfp1c[tid] = FP1[b * Cch + c0 + tid];
            sbgc[tid]  = 0.3f * bgp[b * Cch + c0 + tid];
        }
        f32x4 accp = {};
        uint4 vv = *(const uint4*)(FtB + (size_t)sji[jj] * Cch + c0 + cg * 8);
        for (int j0 = 0; j0 < K64; j0 += 64) {
            __syncthreads();                // Bt free
            {   // gather-transpose: Bt[c][j] <- Ft[ji[j]][c]
                unsigned short* qd = &Bt[cg * 8][jj];
                qd[0]       = (unsigned short)vv.x;  qd[136]     = (unsigned short)(vv.x >> 16);
                qd[2 * 136] = (unsigned short)vv.y;  qd[3 * 136] = (unsigned short)(vv.y >> 16);
                qd[4 * 136] = (unsigned short)vv.z;  qd[5 * 136] = (unsigned short)(vv.z >> 16);
                qd[6 * 136] = (unsigned short)vv.w;  qd[7 * 136] = (unsigned short)(vv.w >> 16);
            }
            __syncthreads();                // V tile ready
            int jn = j0 + 64;
            if (jn < K64) vv = *(const uint4*)(FtB + (size_t)sji[jn + jj] * Cch + c0 + cg * 8);
            #pragma unroll
            for (int hh = 0; hh < 2; hh++) {
                bf16x8 af  = *(const bf16x8*)&Bt[cgw * 16 + ml][hh * 32 + quad * 8];
                bf16x8 bfr = *(const bf16x8*)&sP[icol][j0 + hh * 32 + quad * 8];
                accp = __builtin_amdgcn_mfma_f32_16x16x32_bf16(af, bfr, accp, 0, 0, 0);
            }
        }
        #pragma unroll
        for (int r = 0; r < 4; r++) {
            int cl = cgw * 16 + quad * 4 + r;
            float loc = accp[r] * rdi;
            float bp1 = sbgc[cl] + 0.7f * loc;
            float qv = bf2f(Afull[icol][c0 + cl]);
            sdb += qv * bp1;
            snb += bp1 * bp1;
            sdf += qv * sfp1c[cl];
            sqq += qv * qv;
        }
    }
    // ---- reduce partials (quads within wave, then cross-wave via LDS) ----
    sdb += __shfl_xor(sdb, 16);  sdb += __shfl_xor(sdb, 32);
    snb += __shfl_xor(snb, 16);  snb += __shfl_xor(snb, 32);
    sdf += __shfl_xor(sdf, 16);  sdf += __shfl_xor(sdf, 32);
    sqq += __shfl_xor(sqq, 16);  sqq += __shfl_xor(sqq, 32);
    if (quad == 0) {
        atomicAdd(&spart[icol][0], sdb);
        atomicAdd(&spart[icol][1], snb);
        atomicAdd(&spart[icol][2], sdf);
        atomicAdd(&spart[icol][3], sqq);
    }
    __syncthreads();
    if (tid < 32) {
        float db = spart[tid][0], nb = spart[tid][1];
        float df = spart[tid][2], qq = spart[tid][3];
        float nq = sqrtf(qq);
        float sb2 = 10.f * db / fmaxf(nq * sqrtf(nb), 1e-8f);
        float sf2 = 10.f * df / fmaxf(nq * nfv[b], 1e-8f);
        out[((size_t)b * 2) * Npx + i0 + tid] = sb2;
        out[((size_t)b * 2 + 1) * Npx + i0 + tid] = sf2;
    }
}

extern "C" void kernel_launch(void* const* d_in, const int* in_sizes, int n_in,
                              void* d_out, int out_size, void* d_ws, size_t ws_size,
                              hipStream_t stream) {
    const float* fq = (const float*)d_in[0];
    const float* sf = (const float*)d_in[1];
    const int* mask = (const int*)d_in[2];
    float* out = (float*)d_out;

    float* ws = (float*)d_ws;
    float* FP    = ws;                        // B*C
    float* BP    = FP + Bsz * Cch;
    float* fgp   = BP + Bsz * Cch;
    float* bgp   = fgp + Bsz * Cch;
    float* FP1   = bgp + Bsz * Cch;           // B*C
    float* nfv   = FP1 + Bsz * Cch;           // 8
    float* dsim  = nfv + 8;                   // B*N
    float* invn  = dsim + BN;
    float* ivg   = invn + BN;
    int*   nsf   = (int*)(ivg + BN);          // 8
    int*   nsb   = nsf + 8;                   // 8
    int*   jf    = nsb + 8;                   // B*N
    int*   jb    = jf + BN;                   // B*N
    unsigned short* Ft = (unsigned short*)(jb + BN);                     // 8 MB [i][c]

    k_pool<<<dim3(Cch, Bsz), 256, 0, stream>>>(sf, mask, FP, BP);
    k_predcast<<<dim3(Npx / 32, Bsz), 512, 0, stream>>>(fq, FP, BP, dsim, invn, Ft);
    k_selcompact<<<dim3(2, Bsz), 1024, 0, stream>>>(dsim, invn, Ft, FP, nsf, nsb, jf, jb, ivg, fgp, bgp, FP1, nfv);
    k_fused<<<dim3(32, Bsz), 512, 0, stream>>>(Ft, jb, nsb, invn, ivg, bgp, FP1, nfv, out);
}